// Round 3
// baseline (465.605 us; speedup 1.0000x reference)
//
#include <hip/hip_runtime.h>

#define D 64
#define NPB 64
#define THREADS 512
#define CAP 64
#define GRID 1024
#define NFILLB 896   // fill blocks: 8 XCD groups x 112 chunks; rest convert

typedef int v4i __attribute__((ext_vector_type(4)));   // nt-load-compatible int4
typedef short bf16x8 __attribute__((ext_vector_type(8)));  // MFMA A/B frag (8 bf16)
typedef float f32x4 __attribute__((ext_vector_type(4)));   // MFMA C/D frag

__device__ __forceinline__ unsigned short f2bf(float f) {
  unsigned u = __float_as_uint(f);
  return (unsigned short)((u + 0x7FFFu + ((u >> 16) & 1u)) >> 16);
}
__device__ __forceinline__ float bf2f(unsigned short h) {
  return __uint_as_float(((unsigned)h) << 16);
}
// Split fp32 into hi (truncated bf16) + lo (RNE bf16 of residual).
__device__ __forceinline__ void bfsplit(float v, unsigned short& hi, unsigned short& lo) {
  unsigned u = __float_as_uint(v);
  hi = (unsigned short)(u >> 16);
  float r = v - __uint_as_float(u & 0xFFFF0000u);
  lo = f2bf(r);
}

// Ticket-based grid barrier. Safe because grid==GRID is exactly resident
// (launch_bounds(512,8) -> <=64 VGPR -> 4 blocks/CU x 256 CU = 1024) and
// *bar is zeroed by the host memset before every launch (graph-replay safe:
// targets are computed relative to the ticket, and each launch executes
// exactly 2 barriers). Agent-scope fences give cross-XCD visibility
// (gfx950 fence release/acquire -> buffer_wbl2/buffer_inv).
__device__ __forceinline__ void grid_barrier(int* bar) {
  __syncthreads();
  if (threadIdx.x == 0) {
    __threadfence();   // release: flush this XCD's dirty L2 to LLC
    int ticket = __hip_atomic_fetch_add(bar, 1, __ATOMIC_ACQ_REL,
                                        __HIP_MEMORY_SCOPE_AGENT);
    int target = (ticket / GRID + 1) * GRID;
    while (__hip_atomic_load(bar, __ATOMIC_ACQUIRE,
                             __HIP_MEMORY_SCOPE_AGENT) < target)
      __builtin_amdgcn_s_sleep(16);
    __threadfence();   // acquire: invalidate L1/L2 so we see other XCDs' writes
  }
  __syncthreads();
}

// ---------------------------------------------------------------------------
// ONE persistent kernel, 3 phases, 2 internal grid barriers.
//   A: zero cnt + build W^T hi/lo bf16 planes.
//   B: blocks [0,NFILLB): XCD-partitioned bucket fill (R6/R7-proven, nt edge
//      loads, pre-scaled entries). blocks [NFILLB,GRID): x->bf16 convert —
//      truly concurrent this time (all blocks resident), unlike R2 where
//      2304 blocks > 2048 capacity serialized convert after fill.
//   C: persistent fused gather + 3-term split-bf16 MFMA GEMM (R2 body).
// Removes 2-3 dispatch boundaries worth ~20us each (R1/R2 arithmetic).
// ---------------------------------------------------------------------------
__global__ __launch_bounds__(THREADS, 8) void mega_kernel(
    const float* __restrict__ x, const int* __restrict__ ei,
    const float* __restrict__ W, const float* __restrict__ b,
    float* __restrict__ out, ushort* __restrict__ xh,
    int* __restrict__ cnt, int* __restrict__ sync_base,
    ushort* __restrict__ wth, ushort* __restrict__ wtl,
    int n, int e, int total4, int ntiles, int qpc) {
  __shared__ __align__(16) ushort xsh[NPB * 128];   // 16 KB hi plane
  __shared__ __align__(16) ushort xsl[NPB * 128];   // 16 KB lo plane
  __shared__ int s_tile;

  int* tctr = sync_base;        // phase-C tile counter (memset-zeroed)
  int* bar  = sync_base + 16;   // grid barrier counter (memset-zeroed)

  const int lane = threadIdx.x & 63;
  const int wid  = threadIdx.x >> 6;

  // ---------------- Phase A: zero cnt + Wt planes ----------------
  {
    int gt = blockIdx.x * THREADS + threadIdx.x;
    int gn = GRID * THREADS;
    for (int i = gt; i < n; i += gn) cnt[i] = 0;
    for (int i = gt; i < 2 * D * D; i += gn) {   // Wt[nn][k] = W[k][nn]
      int nn = i >> 7, k = i & 127;
      float v = W[k * D + nn];
      unsigned short hi, lo;
      bfsplit(v, hi, lo);
      wth[i] = hi;
      wtl[i] = lo;
    }
  }
  grid_barrier(bar);

  // ---------------- Phase B: fill (XCD-partitioned) || convert ----------------
  if (blockIdx.x < NFILLB) {
    const int myx = blockIdx.x & 7;
    const int chunk = blockIdx.x >> 3;          // 0..111
    const int quads = e >> 2;
    const v4i* row4 = (const v4i*)ei;
    const v4i* col4 = (const v4i*)(ei + e);
    int* bucket = (int*)out;
    int qend = chunk * qpc + qpc;
    if (qend > quads) qend = quads;
    for (int q = chunk * qpc + threadIdx.x; q < qend; q += THREADS) {
      v4i r = __builtin_nontemporal_load(&row4[q]);
      v4i c = __builtin_nontemporal_load(&col4[q]);
      if (((c.x >> 11) & 7) == myx) {
        int p = atomicAdd(&cnt[c.x], 1);
        if (p < CAP) bucket[(size_t)c.x * CAP + p] = r.x * D;
      }
      if (((c.y >> 11) & 7) == myx) {
        int p = atomicAdd(&cnt[c.y], 1);
        if (p < CAP) bucket[(size_t)c.y * CAP + p] = r.y * D;
      }
      if (((c.z >> 11) & 7) == myx) {
        int p = atomicAdd(&cnt[c.z], 1);
        if (p < CAP) bucket[(size_t)c.z * CAP + p] = r.z * D;
      }
      if (((c.w >> 11) & 7) == myx) {
        int p = atomicAdd(&cnt[c.w], 1);
        if (p < CAP) bucket[(size_t)c.w * CAP + p] = r.w * D;
      }
    }
  } else {
    int t = (blockIdx.x - NFILLB) * THREADS + threadIdx.x;
    int nth = (GRID - NFILLB) * THREADS;
    for (int i = t; i < total4; i += nth) {
      float4 v = ((const float4*)x)[i];
      ushort4 h;
      h.x = f2bf(v.x); h.y = f2bf(v.y); h.z = f2bf(v.z); h.w = f2bf(v.w);
      ((ushort4*)xh)[i] = h;
    }
  }
  grid_barrier(bar);

  // ---------------- Phase C: persistent fused gather + MFMA GEMM ----------------
  const int* bucket = (const int*)out;
  const ushort* xpl = xh + lane;

  // Loop-invariant GEMM geometry.
  const int mt   = wid >> 1;            // m-tile 0..3
  const int nb   = (wid & 1) * 32;      // n base col: 0 or 32
  const int lrow = lane & 15;
  const int kgrp = (lane >> 4) * 8;     // k sub-offset 0/8/16/24
  const int arow = mt * 16 + lrow;
  const int aswz = (arow & 7) << 3;
  const int abase = arow * 128;
  const ushort* wh0 = wth + (nb + lrow) * 128;
  const ushort* wh1 = wth + (nb + 16 + lrow) * 128;
  const ushort* wl0 = wtl + (nb + lrow) * 128;
  const ushort* wl1 = wtl + (nb + 16 + lrow) * 128;
  const float bias0 = b[nb + lrow];
  const float bias1 = b[nb + 16 + lrow];
  const int drow = (lane >> 4) * 4;

  for (;;) {
    if (threadIdx.x == 0) s_tile = atomicAdd(tctr, 1);
    __syncthreads();                    // also orders prior GEMM LDS reads
    const int tile = s_tile;
    if (tile >= ntiles) break;
    const int base = tile * NPB;

    // ---- gather phase, with next-node prefetch ----
    {
      int node0 = base + wid * 8;
      int dgN = 0, bkN = 0;
      float xoN = 0.f;
      if (node0 < n) {
        dgN = cnt[node0];
        bkN = __builtin_nontemporal_load(&bucket[(size_t)node0 * CAP + lane]);
        xoN = __builtin_nontemporal_load(&x[(size_t)node0 * D + lane]);
      }
      for (int m = 0; m < 8; ++m) {
        int nl = wid * 8 + m;
        int node = base + nl;
        int dg = dgN, bk = bkN;
        float xown = xoN;
        if (m < 7) {                    // issue next node's loads NOW
          int nq = node + 1;
          if (nq < n) {
            dgN = cnt[nq];
            bkN = __builtin_nontemporal_load(&bucket[(size_t)nq * CAP + lane]);
            xoN = __builtin_nontemporal_load(&x[(size_t)nq * D + lane]);
          } else {
            dgN = 0; bkN = 0; xoN = 0.f;
          }
        }
        int koff = nl * 128;
        int k0 = lane ^ ((nl & 7) << 3);      // XOR swizzle (element space)
        if (node < n) {
          int dc = dg < CAP ? dg : CAP;
          float s0 = 0.f, s1 = 0.f, s2 = 0.f, s3 = 0.f;
          float s4 = 0.f, s5 = 0.f, s6 = 0.f, s7 = 0.f;
          int p = 0;
          for (; p + 8 <= dc; p += 8) {       // 8 loads in flight
            int a0 = __shfl(bk, p),     a1 = __shfl(bk, p + 1);
            int a2 = __shfl(bk, p + 2), a3 = __shfl(bk, p + 3);
            int a4 = __shfl(bk, p + 4), a5 = __shfl(bk, p + 5);
            int a6 = __shfl(bk, p + 6), a7 = __shfl(bk, p + 7);
            s0 += bf2f(xpl[a0]); s1 += bf2f(xpl[a1]);
            s2 += bf2f(xpl[a2]); s3 += bf2f(xpl[a3]);
            s4 += bf2f(xpl[a4]); s5 += bf2f(xpl[a5]);
            s6 += bf2f(xpl[a6]); s7 += bf2f(xpl[a7]);
          }
          for (; p + 4 <= dc; p += 4) {
            int a0 = __shfl(bk, p),     a1 = __shfl(bk, p + 1);
            int a2 = __shfl(bk, p + 2), a3 = __shfl(bk, p + 3);
            s0 += bf2f(xpl[a0]); s1 += bf2f(xpl[a1]);
            s2 += bf2f(xpl[a2]); s3 += bf2f(xpl[a3]);
          }
          for (; p < dc; ++p)
            s0 += bf2f(xpl[__shfl(bk, p)]);
          float sum = ((s0 + s1) + (s2 + s3)) + ((s4 + s5) + (s6 + s7));
          float inv = (dg > 0) ? (1.0f / (float)dg) : 0.0f;
          float mean = sum * inv;
          unsigned short h, l;
          bfsplit(xown, h, l);
          xsh[koff + k0] = h;       xsl[koff + k0] = l;
          bfsplit(mean, h, l);
          xsh[koff + 64 + k0] = h;  xsl[koff + 64 + k0] = l;
        } else {
          xsh[koff + k0] = 0;       xsl[koff + k0] = 0;
          xsh[koff + 64 + k0] = 0;  xsl[koff + 64 + k0] = 0;
        }
      }
    }
    __syncthreads();

    // ---- MFMA GEMM: out[64][64] = x_aggr[64][128] @ W[128][64] ----
    f32x4 acc0 = {bias0, bias0, bias0, bias0};
    f32x4 acc1 = {bias1, bias1, bias1, bias1};
#pragma unroll 2
    for (int ks = 0; ks < 4; ++ks) {
      int kb = ks * 32 + kgrp;
      int ke = abase + (kb ^ aswz);     // swizzle preserves 8-elem blocks
      bf16x8 ah = *(const bf16x8*)&xsh[ke];
      bf16x8 al = *(const bf16x8*)&xsl[ke];
      bf16x8 w0h = *(const bf16x8*)(wh0 + kb);
      bf16x8 w1h = *(const bf16x8*)(wh1 + kb);
      acc0 = __builtin_amdgcn_mfma_f32_16x16x32_bf16(ah, w0h, acc0, 0, 0, 0);
      acc1 = __builtin_amdgcn_mfma_f32_16x16x32_bf16(ah, w1h, acc1, 0, 0, 0);
      acc0 = __builtin_amdgcn_mfma_f32_16x16x32_bf16(al, w0h, acc0, 0, 0, 0);
      acc1 = __builtin_amdgcn_mfma_f32_16x16x32_bf16(al, w1h, acc1, 0, 0, 0);
      bf16x8 w0l = *(const bf16x8*)(wl0 + kb);
      bf16x8 w1l = *(const bf16x8*)(wl1 + kb);
      acc0 = __builtin_amdgcn_mfma_f32_16x16x32_bf16(ah, w0l, acc0, 0, 0, 0);
      acc1 = __builtin_amdgcn_mfma_f32_16x16x32_bf16(ah, w1l, acc1, 0, 0, 0);
    }

    // Epilogue: C/D layout col=lane&15, row=(lane>>4)*4+r. nt stores.
#pragma unroll
    for (int r = 0; r < 4; ++r) {
      int node = base + mt * 16 + drow + r;
      if (node < n) {
        __builtin_nontemporal_store(fmaxf(acc0[r], 0.0f),
                                    &out[(size_t)node * D + nb + lrow]);
        __builtin_nontemporal_store(fmaxf(acc1[r], 0.0f),
                                    &out[(size_t)node * D + nb + 16 + lrow]);
      }
    }
    __syncthreads();                    // LDS reuse barrier for next tile
  }
}

// ===========================================================================
// Fallback path (R3-proven) if ws can't hold xh + cnt + sync + Wt planes.
// ===========================================================================
__global__ __launch_bounds__(256) void fill_cap_kernel(
    const int* __restrict__ ei, int* __restrict__ cnt,
    int* __restrict__ bucket, int e) {
  int t = blockIdx.x * blockDim.x + threadIdx.x;
  if (t * 4 >= e) return;
  int4 r4 = ((const int4*)ei)[t];
  int4 c4 = ((const int4*)(ei + e))[t];
  int p0 = atomicAdd(&cnt[c4.x], 1);
  int p1 = atomicAdd(&cnt[c4.y], 1);
  int p2 = atomicAdd(&cnt[c4.z], 1);
  int p3 = atomicAdd(&cnt[c4.w], 1);
  if (p0 < CAP) bucket[(size_t)c4.x * CAP + p0] = r4.x;
  if (p1 < CAP) bucket[(size_t)c4.y * CAP + p1] = r4.y;
  if (p2 < CAP) bucket[(size_t)c4.z * CAP + p2] = r4.z;
  if (p3 < CAP) bucket[(size_t)c4.w * CAP + p3] = r4.w;
}

__global__ __launch_bounds__(THREADS, 8) void fused_cap_kernel(
    const float* __restrict__ x, const int* __restrict__ cnt,
    const float* __restrict__ W, const float* __restrict__ b,
    float* __restrict__ out, int n) {
  __shared__ __align__(16) float xs[NPB * 128];
  const int lane = threadIdx.x & 63;
  const int wid  = threadIdx.x >> 6;
  const int base = blockIdx.x * NPB;
  const int* bucket = (const int*)out;

  for (int m = 0; m < 8; ++m) {
    int nl = wid * 8 + m;
    int node = base + nl;
    if (node < n) {
      int dg = cnt[node];
      int dc = dg < CAP ? dg : CAP;
      int bk = bucket[(size_t)node * CAP + lane];
      float xown = x[(size_t)node * D + lane];
      float s0 = 0.f, s1 = 0.f, s2 = 0.f, s3 = 0.f;
      int p = 0;
      for (; p + 4 <= dc; p += 4) {
        int a0 = __shfl(bk, p),     a1 = __shfl(bk, p + 1);
        int a2 = __shfl(bk, p + 2), a3 = __shfl(bk, p + 3);
        s0 += x[(size_t)a0 * D + lane];
        s1 += x[(size_t)a1 * D + lane];
        s2 += x[(size_t)a2 * D + lane];
        s3 += x[(size_t)a3 * D + lane];
      }
      for (; p < dc; ++p)
        s0 += x[(size_t)__shfl(bk, p) * D + lane];
      float sum = (s0 + s1) + (s2 + s3);
      float inv = (dg > 0) ? (1.0f / (float)dg) : 0.0f;
      xs[nl * 128 + lane]      = xown;
      xs[nl * 128 + 64 + lane] = sum * inv;
    } else {
      xs[nl * 128 + lane]      = 0.0f;
      xs[nl * 128 + 64 + lane] = 0.0f;
    }
  }
  __syncthreads();

  const int col = lane;
  float bias = b[col];
  float acc[8];
#pragma unroll
  for (int m = 0; m < 8; ++m) acc[m] = bias;
  for (int k = 0; k < 128; k += 4) {
    float w0 = W[(k + 0) * 64 + col];
    float w1 = W[(k + 1) * 64 + col];
    float w2 = W[(k + 2) * 64 + col];
    float w3 = W[(k + 3) * 64 + col];
#pragma unroll
    for (int m = 0; m < 8; ++m) {
      int nl = wid + m * 8;
      float4 xv = *(const float4*)&xs[nl * 128 + k];
      acc[m] = fmaf(xv.x, w0, acc[m]);
      acc[m] = fmaf(xv.y, w1, acc[m]);
      acc[m] = fmaf(xv.z, w2, acc[m]);
      acc[m] = fmaf(xv.w, w3, acc[m]);
    }
  }
#pragma unroll
  for (int m = 0; m < 8; ++m) {
    int node = base + wid + m * 8;
    if (node < n)
      out[(size_t)node * D + col] = fmaxf(acc[m], 0.0f);
  }
}

extern "C" void kernel_launch(void* const* d_in, const int* in_sizes, int n_in,
                              void* d_out, int out_size, void* d_ws, size_t ws_size,
                              hipStream_t stream) {
  const float* x = (const float*)d_in[0];
  const int* ei = (const int*)d_in[1];
  const float* W = (const float*)d_in[2];
  const float* b = (const float*)d_in[3];
  float* out = (float*)d_out;

  int n = in_sizes[0] / D;            // 100000
  int e = in_sizes[1] / 2;            // 1250000
  int ntiles = (n + NPB - 1) / NPB;   // 1563

  size_t xh_bytes = (size_t)n * D * sizeof(ushort);       // 12.8 MB
  size_t cnt_off  = (xh_bytes + 255) & ~(size_t)255;
  size_t sync_off = (cnt_off + (size_t)n * sizeof(int) + 255) & ~(size_t)255;
  size_t wth_off  = sync_off + 256;
  size_t wtl_off  = wth_off + 2 * D * D * sizeof(ushort);  // +16 KB
  size_t need     = wtl_off + 2 * D * D * sizeof(ushort) + 256;

  if (ws_size >= need && (e & 3) == 0 && n <= (1 << 17)) {
    ushort* xh   = (ushort*)d_ws;
    int* cnt     = (int*)((char*)d_ws + cnt_off);
    int* syncb   = (int*)((char*)d_ws + sync_off);
    ushort* wth  = (ushort*)((char*)d_ws + wth_off);
    ushort* wtl  = (ushort*)((char*)d_ws + wtl_off);

    // Zero tile counter + grid-barrier counter (256 B). cnt is zeroed
    // in-kernel (phase A) — no dependency before the kernel itself.
    (void)hipMemsetAsync((char*)d_ws + sync_off, 0, 256, stream);

    int total4 = n * D / 4;
    int quads = e >> 2;                          // 312500
    int chunks = NFILLB / 8;                     // 112
    int qpc = (quads + chunks - 1) / chunks;     // quads per chunk

    mega_kernel<<<GRID, THREADS, 0, stream>>>(
        x, ei, W, b, out, xh, cnt, syncb, wth, wtl,
        n, e, total4, ntiles, qpc);
  } else {
    int* cnt = (int*)d_ws;
    (void)hipMemsetAsync(cnt, 0, (size_t)n * sizeof(int), stream);
    int quads = e / 4;
    fill_cap_kernel<<<(quads + 255) / 256, 256, 0, stream>>>(ei, cnt, (int*)d_out, e);
    fused_cap_kernel<<<ntiles, THREADS, 0, stream>>>(x, cnt, W, b, out, n);
  }
}

// Round 4
// 327.808 us; speedup vs baseline: 1.4204x; 1.4204x over previous
//
#include <hip/hip_runtime.h>

#define D 64
#define NPB 64
#define THREADS 512
#define CAP 64
#define GRID 1024
#define NFILLB 896   // fill blocks: 8 XCD groups x 112 chunks; rest convert

typedef int v4i __attribute__((ext_vector_type(4)));   // nt-load-compatible int4
typedef short bf16x8 __attribute__((ext_vector_type(8)));  // MFMA A/B frag (8 bf16)
typedef float f32x4 __attribute__((ext_vector_type(4)));   // MFMA C/D frag

__device__ __forceinline__ unsigned short f2bf(float f) {
  unsigned u = __float_as_uint(f);
  return (unsigned short)((u + 0x7FFFu + ((u >> 16) & 1u)) >> 16);
}
__device__ __forceinline__ float bf2f(unsigned short h) {
  return __uint_as_float(((unsigned)h) << 16);
}
// Split fp32 into hi (truncated bf16) + lo (RNE bf16 of residual).
__device__ __forceinline__ void bfsplit(float v, unsigned short& hi, unsigned short& lo) {
  unsigned u = __float_as_uint(v);
  hi = (unsigned short)(u >> 16);
  float r = v - __uint_as_float(u & 0xFFFF0000u);
  lo = f2bf(r);
}

// Grid barrier, R3-bug-fixed.
// R3 evidence: spinning with AGENT-scope ACQUIRE loads emits buffer_inv per
// poll -> continuous full-L2 invalidation on all XCDs -> WRITE_SIZE 64->103MB,
// FETCH 87->135MB, mega 3x slower. Fix: arrival is a RELEASE fetch_add (one
// buffer_wbl2 per block, needed so other XCDs' L2s' dirty data reaches LLC);
// the spin uses RELAXED agent loads (global_load sc1: reads the coherence
// point, NO invalidate); ONE acquire fence (single buffer_inv) after exit.
// Deadlock-safe: GRID==1024 is exactly resident (LDS 32.5KB -> 4 blocks/CU
// x 256 CU; R3 ran to completion proving residency), bar zeroed by host
// memset before every launch (graph-replay safe; single barrier per launch).
__device__ __forceinline__ void grid_barrier(int* bar) {
  __syncthreads();
  if (threadIdx.x == 0) {
    __hip_atomic_fetch_add(bar, 1, __ATOMIC_RELEASE, __HIP_MEMORY_SCOPE_AGENT);
    while (__hip_atomic_load(bar, __ATOMIC_RELAXED, __HIP_MEMORY_SCOPE_AGENT) < GRID)
      __builtin_amdgcn_s_sleep(8);
    __builtin_amdgcn_fence(__ATOMIC_ACQUIRE, "agent");
  }
  __syncthreads();
}

// ---------------------------------------------------------------------------
// ONE persistent kernel, 2 phases, 1 internal grid barrier.
//   B: blocks [0,NFILLB): XCD-partitioned bucket fill (R6/R7-proven, nt edge
//      loads, pre-scaled entries; cnt zeroed by host memset).
//      blocks [NFILLB,GRID): W^T hi/lo planes + x->bf16 convert — truly
//      concurrent (all 1024 blocks resident).
//   C: persistent fused gather + 3-term split-bf16 MFMA GEMM (R2 body).
// Removes ~2 dispatch boundaries worth ~23us each (R2 arithmetic).
// ---------------------------------------------------------------------------
__global__ __launch_bounds__(THREADS, 8) void mega_kernel(
    const float* __restrict__ x, const int* __restrict__ ei,
    const float* __restrict__ W, const float* __restrict__ b,
    float* __restrict__ out, ushort* __restrict__ xh,
    int* __restrict__ cnt, int* __restrict__ sync_base,
    ushort* __restrict__ wth, ushort* __restrict__ wtl,
    int n, int e, int total4, int ntiles, int qpc) {
  __shared__ __align__(16) ushort xsh[NPB * 128];   // 16 KB hi plane
  __shared__ __align__(16) ushort xsl[NPB * 128];   // 16 KB lo plane
  __shared__ int s_tile;

  int* tctr = sync_base;        // phase-C tile counter (memset-zeroed)
  int* bar  = sync_base + 16;   // grid barrier counter (memset-zeroed)

  const int lane = threadIdx.x & 63;
  const int wid  = threadIdx.x >> 6;

  // ---------------- Phase B: fill (XCD-partitioned) || convert+Wt ----------------
  if (blockIdx.x < NFILLB) {
    const int myx = blockIdx.x & 7;
    const int chunk = blockIdx.x >> 3;          // 0..111
    const int quads = e >> 2;
    const v4i* row4 = (const v4i*)ei;
    const v4i* col4 = (const v4i*)(ei + e);
    int* bucket = (int*)out;
    int qend = chunk * qpc + qpc;
    if (qend > quads) qend = quads;
    for (int q = chunk * qpc + threadIdx.x; q < qend; q += THREADS) {
      v4i r = __builtin_nontemporal_load(&row4[q]);
      v4i c = __builtin_nontemporal_load(&col4[q]);
      if (((c.x >> 11) & 7) == myx) {
        int p = atomicAdd(&cnt[c.x], 1);
        if (p < CAP) bucket[(size_t)c.x * CAP + p] = r.x * D;
      }
      if (((c.y >> 11) & 7) == myx) {
        int p = atomicAdd(&cnt[c.y], 1);
        if (p < CAP) bucket[(size_t)c.y * CAP + p] = r.y * D;
      }
      if (((c.z >> 11) & 7) == myx) {
        int p = atomicAdd(&cnt[c.z], 1);
        if (p < CAP) bucket[(size_t)c.z * CAP + p] = r.z * D;
      }
      if (((c.w >> 11) & 7) == myx) {
        int p = atomicAdd(&cnt[c.w], 1);
        if (p < CAP) bucket[(size_t)c.w * CAP + p] = r.w * D;
      }
    }
  } else {
    int t = (blockIdx.x - NFILLB) * THREADS + threadIdx.x;
    int nth = (GRID - NFILLB) * THREADS;
    for (int i = t; i < 2 * D * D; i += nth) {   // Wt[nn][k] = W[k][nn]
      int nn = i >> 7, k = i & 127;
      float v = W[k * D + nn];
      unsigned short hi, lo;
      bfsplit(v, hi, lo);
      wth[i] = hi;
      wtl[i] = lo;
    }
    for (int i = t; i < total4; i += nth) {
      float4 v = ((const float4*)x)[i];
      ushort4 h;
      h.x = f2bf(v.x); h.y = f2bf(v.y); h.z = f2bf(v.z); h.w = f2bf(v.w);
      ((ushort4*)xh)[i] = h;
    }
  }
  grid_barrier(bar);

  // ---------------- Phase C: persistent fused gather + MFMA GEMM ----------------
  const int* bucket = (const int*)out;
  const ushort* xpl = xh + lane;

  // Loop-invariant GEMM geometry.
  const int mt   = wid >> 1;            // m-tile 0..3
  const int nb   = (wid & 1) * 32;      // n base col: 0 or 32
  const int lrow = lane & 15;
  const int kgrp = (lane >> 4) * 8;     // k sub-offset 0/8/16/24
  const int arow = mt * 16 + lrow;
  const int aswz = (arow & 7) << 3;
  const int abase = arow * 128;
  const ushort* wh0 = wth + (nb + lrow) * 128;
  const ushort* wh1 = wth + (nb + 16 + lrow) * 128;
  const ushort* wl0 = wtl + (nb + lrow) * 128;
  const ushort* wl1 = wtl + (nb + 16 + lrow) * 128;
  const float bias0 = b[nb + lrow];
  const float bias1 = b[nb + 16 + lrow];
  const int drow = (lane >> 4) * 4;

  for (;;) {
    if (threadIdx.x == 0) s_tile = atomicAdd(tctr, 1);
    __syncthreads();                    // also orders prior GEMM LDS reads
    const int tile = s_tile;
    if (tile >= ntiles) break;
    const int base = tile * NPB;

    // ---- gather phase, with next-node prefetch ----
    {
      int node0 = base + wid * 8;
      int dgN = 0, bkN = 0;
      float xoN = 0.f;
      if (node0 < n) {
        dgN = cnt[node0];
        bkN = __builtin_nontemporal_load(&bucket[(size_t)node0 * CAP + lane]);
        xoN = __builtin_nontemporal_load(&x[(size_t)node0 * D + lane]);
      }
      for (int m = 0; m < 8; ++m) {
        int nl = wid * 8 + m;
        int node = base + nl;
        int dg = dgN, bk = bkN;
        float xown = xoN;
        if (m < 7) {                    // issue next node's loads NOW
          int nq = node + 1;
          if (nq < n) {
            dgN = cnt[nq];
            bkN = __builtin_nontemporal_load(&bucket[(size_t)nq * CAP + lane]);
            xoN = __builtin_nontemporal_load(&x[(size_t)nq * D + lane]);
          } else {
            dgN = 0; bkN = 0; xoN = 0.f;
          }
        }
        int koff = nl * 128;
        int k0 = lane ^ ((nl & 7) << 3);      // XOR swizzle (element space)
        if (node < n) {
          int dc = dg < CAP ? dg : CAP;
          float s0 = 0.f, s1 = 0.f, s2 = 0.f, s3 = 0.f;
          float s4 = 0.f, s5 = 0.f, s6 = 0.f, s7 = 0.f;
          int p = 0;
          for (; p + 8 <= dc; p += 8) {       // 8 loads in flight
            int a0 = __shfl(bk, p),     a1 = __shfl(bk, p + 1);
            int a2 = __shfl(bk, p + 2), a3 = __shfl(bk, p + 3);
            int a4 = __shfl(bk, p + 4), a5 = __shfl(bk, p + 5);
            int a6 = __shfl(bk, p + 6), a7 = __shfl(bk, p + 7);
            s0 += bf2f(xpl[a0]); s1 += bf2f(xpl[a1]);
            s2 += bf2f(xpl[a2]); s3 += bf2f(xpl[a3]);
            s4 += bf2f(xpl[a4]); s5 += bf2f(xpl[a5]);
            s6 += bf2f(xpl[a6]); s7 += bf2f(xpl[a7]);
          }
          for (; p + 4 <= dc; p += 4) {
            int a0 = __shfl(bk, p),     a1 = __shfl(bk, p + 1);
            int a2 = __shfl(bk, p + 2), a3 = __shfl(bk, p + 3);
            s0 += bf2f(xpl[a0]); s1 += bf2f(xpl[a1]);
            s2 += bf2f(xpl[a2]); s3 += bf2f(xpl[a3]);
          }
          for (; p < dc; ++p)
            s0 += bf2f(xpl[__shfl(bk, p)]);
          float sum = ((s0 + s1) + (s2 + s3)) + ((s4 + s5) + (s6 + s7));
          float inv = (dg > 0) ? (1.0f / (float)dg) : 0.0f;
          float mean = sum * inv;
          unsigned short h, l;
          bfsplit(xown, h, l);
          xsh[koff + k0] = h;       xsl[koff + k0] = l;
          bfsplit(mean, h, l);
          xsh[koff + 64 + k0] = h;  xsl[koff + 64 + k0] = l;
        } else {
          xsh[koff + k0] = 0;       xsl[koff + k0] = 0;
          xsh[koff + 64 + k0] = 0;  xsl[koff + 64 + k0] = 0;
        }
      }
    }
    __syncthreads();

    // ---- MFMA GEMM: out[64][64] = x_aggr[64][128] @ W[128][64] ----
    f32x4 acc0 = {bias0, bias0, bias0, bias0};
    f32x4 acc1 = {bias1, bias1, bias1, bias1};
#pragma unroll 2
    for (int ks = 0; ks < 4; ++ks) {
      int kb = ks * 32 + kgrp;
      int ke = abase + (kb ^ aswz);     // swizzle preserves 8-elem blocks
      bf16x8 ah = *(const bf16x8*)&xsh[ke];
      bf16x8 al = *(const bf16x8*)&xsl[ke];
      bf16x8 w0h = *(const bf16x8*)(wh0 + kb);
      bf16x8 w1h = *(const bf16x8*)(wh1 + kb);
      acc0 = __builtin_amdgcn_mfma_f32_16x16x32_bf16(ah, w0h, acc0, 0, 0, 0);
      acc1 = __builtin_amdgcn_mfma_f32_16x16x32_bf16(ah, w1h, acc1, 0, 0, 0);
      acc0 = __builtin_amdgcn_mfma_f32_16x16x32_bf16(al, w0h, acc0, 0, 0, 0);
      acc1 = __builtin_amdgcn_mfma_f32_16x16x32_bf16(al, w1h, acc1, 0, 0, 0);
      bf16x8 w0l = *(const bf16x8*)(wl0 + kb);
      bf16x8 w1l = *(const bf16x8*)(wl1 + kb);
      acc0 = __builtin_amdgcn_mfma_f32_16x16x32_bf16(ah, w0l, acc0, 0, 0, 0);
      acc1 = __builtin_amdgcn_mfma_f32_16x16x32_bf16(ah, w1l, acc1, 0, 0, 0);
    }

    // Epilogue: C/D layout col=lane&15, row=(lane>>4)*4+r. nt stores.
#pragma unroll
    for (int r = 0; r < 4; ++r) {
      int node = base + mt * 16 + drow + r;
      if (node < n) {
        __builtin_nontemporal_store(fmaxf(acc0[r], 0.0f),
                                    &out[(size_t)node * D + nb + lrow]);
        __builtin_nontemporal_store(fmaxf(acc1[r], 0.0f),
                                    &out[(size_t)node * D + nb + 16 + lrow]);
      }
    }
    __syncthreads();                    // LDS reuse barrier for next tile
  }
}

// ===========================================================================
// Fallback path (R3-proven) if ws can't hold xh + cnt + sync + Wt planes.
// ===========================================================================
__global__ __launch_bounds__(256) void fill_cap_kernel(
    const int* __restrict__ ei, int* __restrict__ cnt,
    int* __restrict__ bucket, int e) {
  int t = blockIdx.x * blockDim.x + threadIdx.x;
  if (t * 4 >= e) return;
  int4 r4 = ((const int4*)ei)[t];
  int4 c4 = ((const int4*)(ei + e))[t];
  int p0 = atomicAdd(&cnt[c4.x], 1);
  int p1 = atomicAdd(&cnt[c4.y], 1);
  int p2 = atomicAdd(&cnt[c4.z], 1);
  int p3 = atomicAdd(&cnt[c4.w], 1);
  if (p0 < CAP) bucket[(size_t)c4.x * CAP + p0] = r4.x;
  if (p1 < CAP) bucket[(size_t)c4.y * CAP + p1] = r4.y;
  if (p2 < CAP) bucket[(size_t)c4.z * CAP + p2] = r4.z;
  if (p3 < CAP) bucket[(size_t)c4.w * CAP + p3] = r4.w;
}

__global__ __launch_bounds__(THREADS, 8) void fused_cap_kernel(
    const float* __restrict__ x, const int* __restrict__ cnt,
    const float* __restrict__ W, const float* __restrict__ b,
    float* __restrict__ out, int n) {
  __shared__ __align__(16) float xs[NPB * 128];
  const int lane = threadIdx.x & 63;
  const int wid  = threadIdx.x >> 6;
  const int base = blockIdx.x * NPB;
  const int* bucket = (const int*)out;

  for (int m = 0; m < 8; ++m) {
    int nl = wid * 8 + m;
    int node = base + nl;
    if (node < n) {
      int dg = cnt[node];
      int dc = dg < CAP ? dg : CAP;
      int bk = bucket[(size_t)node * CAP + lane];
      float xown = x[(size_t)node * D + lane];
      float s0 = 0.f, s1 = 0.f, s2 = 0.f, s3 = 0.f;
      int p = 0;
      for (; p + 4 <= dc; p += 4) {
        int a0 = __shfl(bk, p),     a1 = __shfl(bk, p + 1);
        int a2 = __shfl(bk, p + 2), a3 = __shfl(bk, p + 3);
        s0 += x[(size_t)a0 * D + lane];
        s1 += x[(size_t)a1 * D + lane];
        s2 += x[(size_t)a2 * D + lane];
        s3 += x[(size_t)a3 * D + lane];
      }
      for (; p < dc; ++p)
        s0 += x[(size_t)__shfl(bk, p) * D + lane];
      float sum = (s0 + s1) + (s2 + s3);
      float inv = (dg > 0) ? (1.0f / (float)dg) : 0.0f;
      xs[nl * 128 + lane]      = xown;
      xs[nl * 128 + 64 + lane] = sum * inv;
    } else {
      xs[nl * 128 + lane]      = 0.0f;
      xs[nl * 128 + 64 + lane] = 0.0f;
    }
  }
  __syncthreads();

  const int col = lane;
  float bias = b[col];
  float acc[8];
#pragma unroll
  for (int m = 0; m < 8; ++m) acc[m] = bias;
  for (int k = 0; k < 128; k += 4) {
    float w0 = W[(k + 0) * 64 + col];
    float w1 = W[(k + 1) * 64 + col];
    float w2 = W[(k + 2) * 64 + col];
    float w3 = W[(k + 3) * 64 + col];
#pragma unroll
    for (int m = 0; m < 8; ++m) {
      int nl = wid + m * 8;
      float4 xv = *(const float4*)&xs[nl * 128 + k];
      acc[m] = fmaf(xv.x, w0, acc[m]);
      acc[m] = fmaf(xv.y, w1, acc[m]);
      acc[m] = fmaf(xv.z, w2, acc[m]);
      acc[m] = fmaf(xv.w, w3, acc[m]);
    }
  }
#pragma unroll
  for (int m = 0; m < 8; ++m) {
    int node = base + wid + m * 8;
    if (node < n)
      out[(size_t)node * D + col] = fmaxf(acc[m], 0.0f);
  }
}

extern "C" void kernel_launch(void* const* d_in, const int* in_sizes, int n_in,
                              void* d_out, int out_size, void* d_ws, size_t ws_size,
                              hipStream_t stream) {
  const float* x = (const float*)d_in[0];
  const int* ei = (const int*)d_in[1];
  const float* W = (const float*)d_in[2];
  const float* b = (const float*)d_in[3];
  float* out = (float*)d_out;

  int n = in_sizes[0] / D;            // 100000
  int e = in_sizes[1] / 2;            // 1250000
  int ntiles = (n + NPB - 1) / NPB;   // 1563

  size_t xh_bytes = (size_t)n * D * sizeof(ushort);       // 12.8 MB
  size_t cnt_off  = (xh_bytes + 255) & ~(size_t)255;
  size_t sync_off = (cnt_off + (size_t)n * sizeof(int) + 255) & ~(size_t)255;
  size_t wth_off  = sync_off + 256;
  size_t wtl_off  = wth_off + 2 * D * D * sizeof(ushort);  // +16 KB
  size_t need     = wtl_off + 2 * D * D * sizeof(ushort) + 256;

  if (ws_size >= need && (e & 3) == 0 && n <= (1 << 17)) {
    ushort* xh   = (ushort*)d_ws;
    int* cnt     = (int*)((char*)d_ws + cnt_off);
    int* syncb   = (int*)((char*)d_ws + sync_off);
    ushort* wth  = (ushort*)((char*)d_ws + wth_off);
    ushort* wtl  = (ushort*)((char*)d_ws + wtl_off);

    // One memset zeroes cnt + tile counter + barrier counter (contiguous).
    (void)hipMemsetAsync((char*)d_ws + cnt_off, 0,
                         sync_off + 256 - cnt_off, stream);

    int total4 = n * D / 4;
    int quads = e >> 2;                          // 312500
    int chunks = NFILLB / 8;                     // 112
    int qpc = (quads + chunks - 1) / chunks;     // quads per chunk

    mega_kernel<<<GRID, THREADS, 0, stream>>>(
        x, ei, W, b, out, xh, cnt, syncb, wth, wtl,
        n, e, total4, ntiles, qpc);
  } else {
    int* cnt = (int*)d_ws;
    (void)hipMemsetAsync(cnt, 0, (size_t)n * sizeof(int), stream);
    int quads = e / 4;
    fill_cap_kernel<<<(quads + 255) / 256, 256, 0, stream>>>(ei, cnt, (int*)d_out, e);
    fused_cap_kernel<<<ntiles, THREADS, 0, stream>>>(x, cnt, W, b, out, n);
  }
}

// Round 5
// 202.064 us; speedup vs baseline: 2.3042x; 1.6223x over previous
//
#include <hip/hip_runtime.h>

#define D 64
#define NPB 64
#define THREADS 512
#define CAP 64
#define NFILLB 1792   // fill blocks: 8 XCDs x 224 chunks
#define NCONVB 256    // convert blocks; NFILLB+NCONVB = 2048 = exactly resident
                      // (256-thr blocks, 8 blocks/CU x 256 CU). R2 evidence:
                      // 2304 blocks > 2048 capacity serialized convert after
                      // fill (77.5us); single-round -> true overlap.

typedef int v4i __attribute__((ext_vector_type(4)));   // nt-load-compatible int4
typedef short bf16x8 __attribute__((ext_vector_type(8)));  // MFMA A/B frag (8 bf16)
typedef float f32x4 __attribute__((ext_vector_type(4)));   // MFMA C/D frag

__device__ __forceinline__ unsigned short f2bf(float f) {
  unsigned u = __float_as_uint(f);
  return (unsigned short)((u + 0x7FFFu + ((u >> 16) & 1u)) >> 16);
}
__device__ __forceinline__ float bf2f(unsigned short h) {
  return __uint_as_float(((unsigned)h) << 16);
}
// Split fp32 into hi (truncated bf16) + lo (RNE bf16 of residual).
__device__ __forceinline__ void bfsplit(float v, unsigned short& hi, unsigned short& lo) {
  unsigned u = __float_as_uint(v);
  hi = (unsigned short)(u >> 16);
  float r = v - __uint_as_float(u & 0xFFFF0000u);
  lo = f2bf(r);
}

// ---------------------------------------------------------------------------
// Dispatch 1 (after cnt memset): fill || convert, capacity-correct.
//   blocks [0,NFILLB):    XCD-partitioned bucket fill (R6/R7-proven: nt edge
//                         loads keep the dirty bucket slab L2-resident;
//                         pre-scaled entries src*64).
//   blocks [NFILLB,2048): W^T hi/lo bf16 planes + x->bf16 convert. Only
//                         needed before the NEXT dispatch; overlaps fill.
// ---------------------------------------------------------------------------
__global__ __launch_bounds__(256, 8) void fill_prep_kernel(
    const int* __restrict__ ei, int* __restrict__ cnt,
    int* __restrict__ bucket, int e, int qpc,
    const float* __restrict__ x, ushort* __restrict__ xh,
    const float* __restrict__ W, ushort* __restrict__ wth,
    ushort* __restrict__ wtl, int n, int total4) {
  if (blockIdx.x < NFILLB) {
    const int myx = blockIdx.x & 7;
    const int chunk = blockIdx.x >> 3;          // 0..223
    const int quads = e >> 2;
    const v4i* row4 = (const v4i*)ei;
    const v4i* col4 = (const v4i*)(ei + e);
    int qend = chunk * qpc + qpc;
    if (qend > quads) qend = quads;
    for (int q = chunk * qpc + threadIdx.x; q < qend; q += 256) {
      v4i r = __builtin_nontemporal_load(&row4[q]);
      v4i c = __builtin_nontemporal_load(&col4[q]);
      if (((c.x >> 11) & 7) == myx) {
        int p = atomicAdd(&cnt[c.x], 1);
        if (p < CAP) bucket[(size_t)c.x * CAP + p] = r.x * D;
      }
      if (((c.y >> 11) & 7) == myx) {
        int p = atomicAdd(&cnt[c.y], 1);
        if (p < CAP) bucket[(size_t)c.y * CAP + p] = r.y * D;
      }
      if (((c.z >> 11) & 7) == myx) {
        int p = atomicAdd(&cnt[c.z], 1);
        if (p < CAP) bucket[(size_t)c.z * CAP + p] = r.z * D;
      }
      if (((c.w >> 11) & 7) == myx) {
        int p = atomicAdd(&cnt[c.w], 1);
        if (p < CAP) bucket[(size_t)c.w * CAP + p] = r.w * D;
      }
    }
  } else {
    int t = (blockIdx.x - NFILLB) * 256 + threadIdx.x;
    int nth = NCONVB * 256;
    for (int i = t; i < 2 * D * D; i += nth) {   // Wt[nn][k] = W[k][nn]
      int nn = i >> 7, k = i & 127;
      float v = W[k * D + nn];
      unsigned short hi, lo;
      bfsplit(v, hi, lo);
      wth[i] = hi;
      wtl[i] = lo;
    }
    for (int i = t; i < total4; i += nth) {
      float4 v = ((const float4*)x)[i];
      ushort4 h;
      h.x = f2bf(v.x); h.y = f2bf(v.y); h.z = f2bf(v.z); h.w = f2bf(v.w);
      ((ushort4*)xh)[i] = h;
    }
  }
}

// ---------------------------------------------------------------------------
// Dispatch 2: fused consume — EXACT R1 body (measured 72.5us standalone).
// R2-R4 lesson: the persistent/atomic-claim/prefetch/nt variant of this
// kernel regressed to ~105-120us; do not bundle unverified changes onto it.
// Wave per 8 nodes, lane = feature, 8-deep bf16 gather (pre-scaled offsets)
// -> hi/lo bf16 LDS planes (XOR-swizzled) -> 24-MFMA 3-term split-bf16 GEMM
// (== fp32 accuracy). C/D layout: col=lane&15, row=(lane>>4)*4+reg.
// ---------------------------------------------------------------------------
__global__ __launch_bounds__(THREADS, 8) void fused_bf_kernel(
    const float* __restrict__ x, const ushort* __restrict__ xh,
    const int* __restrict__ cnt,
    const ushort* __restrict__ wth, const ushort* __restrict__ wtl,
    const float* __restrict__ b, float* __restrict__ out, int n) {
  __shared__ __align__(16) ushort xsh[NPB * 128];   // 16 KB hi plane
  __shared__ __align__(16) ushort xsl[NPB * 128];   // 16 KB lo plane

  const int lane = threadIdx.x & 63;
  const int wid  = threadIdx.x >> 6;
  const int base = blockIdx.x * NPB;
  const int* bucket = (const int*)out;
  const ushort* xpl = xh + lane;

  for (int m = 0; m < 8; ++m) {
    int nl = wid * 8 + m;
    int node = base + nl;
    int koff = nl * 128;
    int k0 = lane ^ ((nl & 7) << 3);          // XOR swizzle (element space)
    if (node < n) {
      int dg = cnt[node];
      int dc = dg < CAP ? dg : CAP;
      int bk = bucket[(size_t)node * CAP + lane];   // coalesced 256B
      float xown = x[(size_t)node * D + lane];
      float s0 = 0.f, s1 = 0.f, s2 = 0.f, s3 = 0.f;
      float s4 = 0.f, s5 = 0.f, s6 = 0.f, s7 = 0.f;
      int p = 0;
      for (; p + 8 <= dc; p += 8) {                 // 8 loads in flight
        int a0 = __shfl(bk, p),     a1 = __shfl(bk, p + 1);
        int a2 = __shfl(bk, p + 2), a3 = __shfl(bk, p + 3);
        int a4 = __shfl(bk, p + 4), a5 = __shfl(bk, p + 5);
        int a6 = __shfl(bk, p + 6), a7 = __shfl(bk, p + 7);
        s0 += bf2f(xpl[a0]); s1 += bf2f(xpl[a1]);
        s2 += bf2f(xpl[a2]); s3 += bf2f(xpl[a3]);
        s4 += bf2f(xpl[a4]); s5 += bf2f(xpl[a5]);
        s6 += bf2f(xpl[a6]); s7 += bf2f(xpl[a7]);
      }
      for (; p + 4 <= dc; p += 4) {
        int a0 = __shfl(bk, p),     a1 = __shfl(bk, p + 1);
        int a2 = __shfl(bk, p + 2), a3 = __shfl(bk, p + 3);
        s0 += bf2f(xpl[a0]); s1 += bf2f(xpl[a1]);
        s2 += bf2f(xpl[a2]); s3 += bf2f(xpl[a3]);
      }
      for (; p < dc; ++p)
        s0 += bf2f(xpl[__shfl(bk, p)]);
      float sum = ((s0 + s1) + (s2 + s3)) + ((s4 + s5) + (s6 + s7));
      float inv = (dg > 0) ? (1.0f / (float)dg) : 0.0f;
      float mean = sum * inv;
      unsigned short h, l;
      bfsplit(xown, h, l);
      xsh[koff + k0] = h;       xsl[koff + k0] = l;
      bfsplit(mean, h, l);
      xsh[koff + 64 + k0] = h;  xsl[koff + 64 + k0] = l;
    } else {
      xsh[koff + k0] = 0;       xsl[koff + k0] = 0;
      xsh[koff + 64 + k0] = 0;  xsl[koff + 64 + k0] = 0;
    }
  }
  __syncthreads();

  // ---- MFMA GEMM: out[64 nodes][64 cols] = x_aggr[64][128] @ W[128][64] ----
  const int mt   = wid >> 1;            // m-tile 0..3
  const int nb   = (wid & 1) * 32;      // n base col: 0 or 32
  const int lrow = lane & 15;
  const int kgrp = (lane >> 4) * 8;     // k sub-offset 0/8/16/24

  const int arow = mt * 16 + lrow;      // A fragment row (local node)
  const int aswz = (arow & 7) << 3;
  const int abase = arow * 128;

  const ushort* wh0 = wth + (nb + lrow) * 128;
  const ushort* wh1 = wth + (nb + 16 + lrow) * 128;
  const ushort* wl0 = wtl + (nb + lrow) * 128;
  const ushort* wl1 = wtl + (nb + 16 + lrow) * 128;

  float bias0 = b[nb + lrow];
  float bias1 = b[nb + 16 + lrow];
  f32x4 acc0 = {bias0, bias0, bias0, bias0};
  f32x4 acc1 = {bias1, bias1, bias1, bias1};

#pragma unroll 2
  for (int ks = 0; ks < 4; ++ks) {
    int kb = ks * 32 + kgrp;
    int ke = abase + (kb ^ aswz);       // swizzle preserves 8-elem blocks
    bf16x8 ah = *(const bf16x8*)&xsh[ke];
    bf16x8 al = *(const bf16x8*)&xsl[ke];
    bf16x8 w0h = *(const bf16x8*)(wh0 + kb);
    bf16x8 w1h = *(const bf16x8*)(wh1 + kb);
    acc0 = __builtin_amdgcn_mfma_f32_16x16x32_bf16(ah, w0h, acc0, 0, 0, 0);
    acc1 = __builtin_amdgcn_mfma_f32_16x16x32_bf16(ah, w1h, acc1, 0, 0, 0);
    acc0 = __builtin_amdgcn_mfma_f32_16x16x32_bf16(al, w0h, acc0, 0, 0, 0);
    acc1 = __builtin_amdgcn_mfma_f32_16x16x32_bf16(al, w1h, acc1, 0, 0, 0);
    bf16x8 w0l = *(const bf16x8*)(wl0 + kb);
    bf16x8 w1l = *(const bf16x8*)(wl1 + kb);
    acc0 = __builtin_amdgcn_mfma_f32_16x16x32_bf16(ah, w0l, acc0, 0, 0, 0);
    acc1 = __builtin_amdgcn_mfma_f32_16x16x32_bf16(ah, w1l, acc1, 0, 0, 0);
  }

  // Epilogue: C/D layout col=lane&15, row=(lane>>4)*4+r
  const int drow = (lane >> 4) * 4;
#pragma unroll
  for (int r = 0; r < 4; ++r) {
    int node = base + mt * 16 + drow + r;
    if (node < n) {
      out[(size_t)node * D + nb + lrow]      = fmaxf(acc0[r], 0.0f);
      out[(size_t)node * D + nb + 16 + lrow] = fmaxf(acc1[r], 0.0f);
    }
  }
}

// ===========================================================================
// Fallback path (R3-proven) if ws can't hold xh + cnt + Wt planes.
// ===========================================================================
__global__ __launch_bounds__(256) void fill_cap_kernel(
    const int* __restrict__ ei, int* __restrict__ cnt,
    int* __restrict__ bucket, int e) {
  int t = blockIdx.x * blockDim.x + threadIdx.x;
  if (t * 4 >= e) return;
  int4 r4 = ((const int4*)ei)[t];
  int4 c4 = ((const int4*)(ei + e))[t];
  int p0 = atomicAdd(&cnt[c4.x], 1);
  int p1 = atomicAdd(&cnt[c4.y], 1);
  int p2 = atomicAdd(&cnt[c4.z], 1);
  int p3 = atomicAdd(&cnt[c4.w], 1);
  if (p0 < CAP) bucket[(size_t)c4.x * CAP + p0] = r4.x;
  if (p1 < CAP) bucket[(size_t)c4.y * CAP + p1] = r4.y;
  if (p2 < CAP) bucket[(size_t)c4.z * CAP + p2] = r4.z;
  if (p3 < CAP) bucket[(size_t)c4.w * CAP + p3] = r4.w;
}

__global__ __launch_bounds__(THREADS, 8) void fused_cap_kernel(
    const float* __restrict__ x, const int* __restrict__ cnt,
    const float* __restrict__ W, const float* __restrict__ b,
    float* __restrict__ out, int n) {
  __shared__ __align__(16) float xs[NPB * 128];
  const int lane = threadIdx.x & 63;
  const int wid  = threadIdx.x >> 6;
  const int base = blockIdx.x * NPB;
  const int* bucket = (const int*)out;

  for (int m = 0; m < 8; ++m) {
    int nl = wid * 8 + m;
    int node = base + nl;
    if (node < n) {
      int dg = cnt[node];
      int dc = dg < CAP ? dg : CAP;
      int bk = bucket[(size_t)node * CAP + lane];
      float xown = x[(size_t)node * D + lane];
      float s0 = 0.f, s1 = 0.f, s2 = 0.f, s3 = 0.f;
      int p = 0;
      for (; p + 4 <= dc; p += 4) {
        int a0 = __shfl(bk, p),     a1 = __shfl(bk, p + 1);
        int a2 = __shfl(bk, p + 2), a3 = __shfl(bk, p + 3);
        s0 += x[(size_t)a0 * D + lane];
        s1 += x[(size_t)a1 * D + lane];
        s2 += x[(size_t)a2 * D + lane];
        s3 += x[(size_t)a3 * D + lane];
      }
      for (; p < dc; ++p)
        s0 += x[(size_t)__shfl(bk, p) * D + lane];
      float sum = (s0 + s1) + (s2 + s3);
      float inv = (dg > 0) ? (1.0f / (float)dg) : 0.0f;
      xs[nl * 128 + lane]      = xown;
      xs[nl * 128 + 64 + lane] = sum * inv;
    } else {
      xs[nl * 128 + lane]      = 0.0f;
      xs[nl * 128 + 64 + lane] = 0.0f;
    }
  }
  __syncthreads();

  const int col = lane;
  float bias = b[col];
  float acc[8];
#pragma unroll
  for (int m = 0; m < 8; ++m) acc[m] = bias;
  for (int k = 0; k < 128; k += 4) {
    float w0 = W[(k + 0) * 64 + col];
    float w1 = W[(k + 1) * 64 + col];
    float w2 = W[(k + 2) * 64 + col];
    float w3 = W[(k + 3) * 64 + col];
#pragma unroll
    for (int m = 0; m < 8; ++m) {
      int nl = wid + m * 8;
      float4 xv = *(const float4*)&xs[nl * 128 + k];
      acc[m] = fmaf(xv.x, w0, acc[m]);
      acc[m] = fmaf(xv.y, w1, acc[m]);
      acc[m] = fmaf(xv.z, w2, acc[m]);
      acc[m] = fmaf(xv.w, w3, acc[m]);
    }
  }
#pragma unroll
  for (int m = 0; m < 8; ++m) {
    int node = base + wid + m * 8;
    if (node < n)
      out[(size_t)node * D + col] = fmaxf(acc[m], 0.0f);
  }
}

extern "C" void kernel_launch(void* const* d_in, const int* in_sizes, int n_in,
                              void* d_out, int out_size, void* d_ws, size_t ws_size,
                              hipStream_t stream) {
  const float* x = (const float*)d_in[0];
  const int* ei = (const int*)d_in[1];
  const float* W = (const float*)d_in[2];
  const float* b = (const float*)d_in[3];
  float* out = (float*)d_out;

  int n = in_sizes[0] / D;            // 100000
  int e = in_sizes[1] / 2;            // 1250000
  int nblocks = (n + NPB - 1) / NPB;  // 1563

  size_t xh_bytes = (size_t)n * D * sizeof(ushort);       // 12.8 MB
  size_t cnt_off  = (xh_bytes + 255) & ~(size_t)255;
  size_t wth_off  = (cnt_off + (size_t)n * sizeof(int) + 255) & ~(size_t)255;
  size_t wtl_off  = wth_off + 2 * D * D * sizeof(ushort);  // +16 KB
  size_t need     = wtl_off + 2 * D * D * sizeof(ushort) + 256;

  if (ws_size >= need && (e & 3) == 0 && n <= (1 << 17)) {
    ushort* xh   = (ushort*)d_ws;
    int* cnt     = (int*)((char*)d_ws + cnt_off);
    ushort* wth  = (ushort*)((char*)d_ws + wth_off);
    ushort* wtl  = (ushort*)((char*)d_ws + wtl_off);

    (void)hipMemsetAsync(cnt, 0, (size_t)n * sizeof(int), stream);

    int total4 = n * D / 4;
    int quads = e >> 2;                          // 312500
    int chunks = NFILLB / 8;                     // 224
    int qpc = (quads + chunks - 1) / chunks;     // 1396 quads per chunk

    fill_prep_kernel<<<NFILLB + NCONVB, 256, 0, stream>>>(
        ei, cnt, (int*)d_out, e, qpc, x, xh, W, wth, wtl, n, total4);

    fused_bf_kernel<<<nblocks, THREADS, 0, stream>>>(
        x, xh, cnt, wth, wtl, b, out, n);
  } else {
    int* cnt = (int*)d_ws;
    (void)hipMemsetAsync(cnt, 0, (size_t)n * sizeof(int), stream);
    int quads = e / 4;
    fill_cap_kernel<<<(quads + 255) / 256, 256, 0, stream>>>(ei, cnt, (int*)d_out, e);
    fused_cap_kernel<<<nblocks, THREADS, 0, stream>>>(x, cnt, W, b, out, n);
  }
}